// Round 22
// baseline (102.912 us; speedup 1.0000x reference)
//
#include <hip/hip_runtime.h>

typedef _Float16 f16;
typedef _Float16 f16x2 __attribute__((ext_vector_type(2)));
typedef _Float16 f16x4 __attribute__((ext_vector_type(4)));
typedef _Float16 f16x8 __attribute__((ext_vector_type(8)));
typedef float    f32x4 __attribute__((ext_vector_type(4)));
typedef float    f32x16 __attribute__((ext_vector_type(16)));
typedef int      i32x4 __attribute__((ext_vector_type(4)));

#define NHEADS 16
#define DK 64
#define BATCH 2
#define SEQ 2048
#define DMODEL 1024
#define MTOT (BATCH*SEQ)          // 4096
#define NQKV (3*DMODEL)           // 3072
#define NBH  (BATCH*NHEADS)       // 32
#define LOG2E 1.44269504f
#define QSCALE (0.125f * LOG2E)   // fold 1/sqrt(dk) and log2(e) into Q
#define MASKVAL (-10000.0f * LOG2E)

__device__ inline f16x8 ld_f16x8_g(const f16* p) {
  return __builtin_bit_cast(f16x8, *reinterpret_cast<const i32x4*>(p));
}

__device__ inline f16x2 cvt_pk(float a, float b) {
  return __builtin_bit_cast(f16x2, __builtin_amdgcn_cvt_pkrtz(a, b));
}

__device__ inline void gl_lds16(const void* g, void* l) {
  __builtin_amdgcn_global_load_lds(
      (const __attribute__((address_space(1))) unsigned int*)g,
      (__attribute__((address_space(3))) unsigned int*)l, 16, 0, 0);
}

// sigma: swap bits 2,3 (involution) -- the V^T column permutation for 32x32 PV
__device__ inline int sigma_k(int s) {
  return (s & ~12) | ((s & 4) << 1) | ((s & 8) >> 1);
}

// ---------------- fused preprocessing: cvt + 2 tcvts + mask scan -----------------
__device__ inline void tcvt_tile(float (*tile)[33], const float* __restrict__ in,
                                 f16* __restrict__ out, int K, int N, int k0, int n0) {
  const int t = threadIdx.x, j = t & 7, ty = t >> 3;   // j: 4-col group, ty: row 0..31
  float4 v = *reinterpret_cast<const float4*>(in + (size_t)(k0 + ty) * N + n0 + j*4);
  tile[ty][j*4+0] = v.x; tile[ty][j*4+1] = v.y;
  tile[ty][j*4+2] = v.z; tile[ty][j*4+3] = v.w;
  __syncthreads();
  union { f16x2 h2[2]; f16x4 h4; } u;
  u.h2[0] = cvt_pk(tile[j*4+0][ty], tile[j*4+1][ty]);
  u.h2[1] = cvt_pk(tile[j*4+2][ty], tile[j*4+3][ty]);
  *(f16x4*)(out + (size_t)(n0 + ty) * K + k0 + j*4) = u.h4;
}

__global__ __launch_bounds__(256) void k_prep(
    const float* __restrict__ x, f16* __restrict__ xh,
    const float* __restrict__ Wqkv, f16* __restrict__ Wqkvt,
    const float* __restrict__ Wout, f16* __restrict__ Woutt,
    const int* __restrict__ mask, int* __restrict__ inv, int* __restrict__ cnt)
{
  __shared__ float tile[32][33];
  __shared__ int part[256];
  const int bid = blockIdx.x;
  const int t = threadIdx.x;
  if (bid < 4096) {
    int i = (bid * 256 + t) * 4;
    float4 v = *reinterpret_cast<const float4*>(x + i);
    f16x4 o = { (f16)v.x, (f16)v.y, (f16)v.z, (f16)v.w };
    *reinterpret_cast<f16x4*>(xh + i) = o;
  } else if (bid < 4096 + 3072) {
    int tl = bid - 4096;                       // 96 n-tiles x 32 k-tiles
    tcvt_tile(tile, Wqkv, Wqkvt, DMODEL, NQKV, (tl / 96) * 32, (tl % 96) * 32);
  } else if (bid < 8192) {
    int tl = bid - 4096 - 3072;                // 32 x 32
    tcvt_tile(tile, Wout, Woutt, DMODEL, DMODEL, (tl / 32) * 32, (tl % 32) * 32);
  } else {
    // deterministic per-batch scan
    const int b = bid - 8192;
    const int* mp = mask + b * SEQ;
    int* iv = inv + b * SEQ;
    const int base = t * 8;
    int m[8]; int s = 0;
    #pragma unroll
    for (int i = 0; i < 8; ++i) { m[i] = mp[base + i]; s += (m[i] != 0); }
    part[t] = s;
    __syncthreads();
    for (int d = 1; d < 256; d <<= 1) {
      int v = (t >= d) ? part[t - d] : 0;
      __syncthreads();
      part[t] += v;
      __syncthreads();
    }
    int pos = (t == 0) ? 0 : part[t - 1];
    #pragma unroll
    for (int i = 0; i < 8; ++i) {
      if (m[i] != 0) { iv[pos] = base + i; ++pos; }
    }
    if (t == 255) cnt[b] = part[255];
  }
}

// ---------------- merged QKV GEMM, DOUBLE-BUFFERED 64x128 tile -------------------
__global__ __launch_bounds__(256, 2) void k_gemm_qkv2(
    const f16* __restrict__ A, const f16* __restrict__ Bt,
    const float* __restrict__ bias, const int* __restrict__ inv,
    const int* __restrict__ cnt,
    f16* __restrict__ qo, f16* __restrict__ ko, f16* __restrict__ vto, int K)
{
  __shared__ f16 As[2][64][64];    // 16 KB
  __shared__ f16 Bs[2][128][64];   // 32 KB
  const int bid = blockIdx.x;
  const bool isQ = bid < 512;

  const int t = threadIdx.x;
  const int l = t & 63, w = t >> 6;
  const int lc = l & 15, g = l >> 4;
  const int srow = l >> 3;
  const int ssl  = ((l & 7) ^ srow) * 16;
  const int swz  = (lc & 7) << 4;

  int m0, n0, b = 0, c = 0;
  const f16* Btp;
  const float* biasp;
  size_t aoff[2];
  if (isQ) {
    n0 = (bid & 7) * 128;  m0 = (bid >> 3) * 64;
    Btp = Bt;  biasp = bias;
    #pragma unroll
    for (int it = 0; it < 2; ++it)
      aoff[it] = (size_t)(m0 + it*32 + w*8 + srow) * K;
  } else {
    const int idx = bid - 512;
    n0 = (idx & 15) * 128;  m0 = (idx >> 4) * 64;
    b = m0 >> 11;
    const int sl0 = m0 & (SEQ - 1);
    c = cnt[b];
    if (sl0 >= ((c + 63) & ~63)) return;    // block-uniform early exit
    Btp = Bt + (size_t)DMODEL * DMODEL;     // K/V weight rows
    biasp = bias + DMODEL;
    #pragma unroll
    for (int it = 0; it < 2; ++it) {
      int slot = sl0 + it*32 + w*8 + srow;
      int sidx = (slot < c) ? slot : (c > 0 ? c - 1 : 0);
      aoff[it] = (size_t)(b * SEQ + (inv[b * SEQ + sidx] & (SEQ - 1))) * K;
    }
  }

  auto stage = [&](int buf, int kt) {
    #pragma unroll
    for (int it = 0; it < 2; ++it)
      gl_lds16((const char*)(A + aoff[it] + kt) + ssl, &As[buf][it*32 + w*8][0]);
    #pragma unroll
    for (int it = 0; it < 4; ++it) {
      int row = it*32 + w*8 + srow;
      gl_lds16((const char*)(Btp + (size_t)(n0 + row) * K + kt) + ssl,
               &Bs[buf][it*32 + w*8][0]);
    }
  };

  f32x4 acc[4][2] = {};
  const int NTk = K >> 6;
  stage(0, 0);

  for (int ti = 0; ti < NTk; ++ti) {
    __syncthreads();                          // stage(ti) complete
    if (ti + 1 < NTk) stage((ti + 1) & 1, (ti + 1) * 64);
    const char* abase = (const char*)&As[ti & 1][0][0];
    const char* bbase = (const char*)&Bs[ti & 1][0][0];
    #pragma unroll
    for (int ks = 0; ks < 64; ks += 32) {
      f16x8 af[4], bf[2];
      #pragma unroll
      for (int i = 0; i < 4; ++i)
        af[i] = *(const f16x8*)(abase + (i*16 + lc)*128 + ((ks*2 + g*16) ^ swz));
      #pragma unroll
      for (int j = 0; j < 2; ++j)
        bf[j] = *(const f16x8*)(bbase + (w*32 + j*16 + lc)*128 + ((ks*2 + g*16) ^ swz));
      #pragma unroll
      for (int i = 0; i < 4; ++i)
        #pragma unroll
        for (int j = 0; j < 2; ++j)
          acc[i][j] = __builtin_amdgcn_mfma_f32_16x16x32_f16(af[i], bf[j], acc[i][j], 0, 0, 0);
    }
  }

  if (isQ) {
    #pragma unroll
    for (int i = 0; i < 4; ++i) {
      const int row0 = m0 + i*16 + g*4;
      const int qb = row0 >> 11, s0 = row0 & (SEQ - 1);
      #pragma unroll
      for (int j = 0; j < 2; ++j) {
        int col = n0 + w*32 + j*16 + lc;      // [0,1024)
        float bv = biasp[col];
        int h = col >> 6, d = col & 63;
        size_t bh = (size_t)(qb * NHEADS + h);
        #pragma unroll
        for (int r = 0; r < 4; ++r)
          qo[(bh * SEQ + s0 + r) * DK + d] = (f16)((acc[i][j][r] + bv) * QSCALE);
      }
    }
  } else {
    const int sl0 = m0 & (SEQ - 1);
    #pragma unroll
    for (int i = 0; i < 4; ++i) {
      const int slot0 = sl0 + i*16 + g*4;     // 4-aligned; sigma(slot0)+r contiguous
      #pragma unroll
      for (int j = 0; j < 2; ++j) {
        int colkv = n0 + w*32 + j*16 + lc;    // [0,2048)
        float bv = biasp[colkv];
        int kv = colkv >> 10;                 // block-uniform
        int h = (colkv >> 6) & 15, d = colkv & 63;
        size_t bh = (size_t)(b * NHEADS + h);
        if (kv == 0) {
          #pragma unroll
          for (int r = 0; r < 4; ++r)
            ko[(bh * SEQ + slot0 + r) * DK + d] = (f16)(acc[i][j][r] + bv);
        } else {
          union { f16x2 h2[2]; f16x4 h4; } u;
          u.h2[0] = cvt_pk(acc[i][j][0] + bv, acc[i][j][1] + bv);
          u.h2[1] = cvt_pk(acc[i][j][2] + bv, acc[i][j][3] + bv);
          *(f16x4*)(vto + (bh * DK + d) * SEQ + sigma_k(slot0)) = u.h4;
        }
      }
    }
  }
}

// ---------------- out-proj GEMM, DOUBLE-BUFFERED 64x128 tile ---------------------
__global__ __launch_bounds__(256, 2) void k_gemm_out(
    const f16* __restrict__ A, const f16* __restrict__ Bt,
    const float* __restrict__ bias, float* __restrict__ outf, int N, int K)
{
  __shared__ f16 As[2][64][64];    // 16 KB
  __shared__ f16 Bs[2][128][64];   // 32 KB
  const int m0 = blockIdx.y * 64, n0 = blockIdx.x * 128;
  const int t = threadIdx.x;
  const int l = t & 63, w = t >> 6;
  const int lc = l & 15, g = l >> 4;
  const int srow = l >> 3;
  const int ssl  = ((l & 7) ^ srow) * 16;
  const int swz  = (lc & 7) << 4;

  auto stage = [&](int buf, int kt) {
    #pragma unroll
    for (int it = 0; it < 2; ++it) {
      int row = it*32 + w*8 + srow;
      gl_lds16((const char*)(A + (size_t)(m0 + row) * K + kt) + ssl,
               &As[buf][it*32 + w*8][0]);
    }
    #pragma unroll
    for (int it = 0; it < 4; ++it) {
      int row = it*32 + w*8 + srow;
      gl_lds16((const char*)(Bt + (size_t)(n0 + row) * K + kt) + ssl,
               &Bs[buf][it*32 + w*8][0]);
    }
  };

  f32x4 acc[4][2] = {};
  const int NTk = K >> 6;
  stage(0, 0);

  for (int ti = 0; ti < NTk; ++ti) {
    __syncthreads();
    if (ti + 1 < NTk) stage((ti + 1) & 1, (ti + 1) * 64);
    const char* abase = (const char*)&As[ti & 1][0][0];
    const char* bbase = (const char*)&Bs[ti & 1][0][0];
    #pragma unroll
    for (int ks = 0; ks < 64; ks += 32) {
      f16x8 af[4], bf[2];
      #pragma unroll
      for (int i = 0; i < 4; ++i)
        af[i] = *(const f16x8*)(abase + (i*16 + lc)*128 + ((ks*2 + g*16) ^ swz));
      #pragma unroll
      for (int j = 0; j < 2; ++j)
        bf[j] = *(const f16x8*)(bbase + (w*32 + j*16 + lc)*128 + ((ks*2 + g*16) ^ swz));
      #pragma unroll
      for (int i = 0; i < 4; ++i)
        #pragma unroll
        for (int j = 0; j < 2; ++j)
          acc[i][j] = __builtin_amdgcn_mfma_f32_16x16x32_f16(af[i], bf[j], acc[i][j], 0, 0, 0);
    }
  }

  #pragma unroll
  for (int i = 0; i < 4; ++i) {
    #pragma unroll
    for (int j = 0; j < 2; ++j) {
      int col = n0 + w*32 + j*16 + lc;
      float bv = bias[col];
      #pragma unroll
      for (int r = 0; r < 4; ++r) {
        int row = m0 + i*16 + g*4 + r;
        outf[(size_t)row * N + col] = acc[i][j][r] + bv;
      }
    }
  }
}

// ---------------- flash attention v13: K in LDS, V direct from L2 ----------------
// 512 blocks x 256 thr; wave owns 32 q. Per-CU LDS traffic halved vs v10:
// only K staged (16 KB/block) + K frag reads; V fragments read straight from
// global (compacted V' is L2-resident per XCD), issued right after the barrier
// so QK-MFMA + softmax (~360 cyc) covers L2 latency.
__global__ __launch_bounds__(256, 2) void k_attn13(
    const f16* __restrict__ Q, const f16* __restrict__ K,
    const f16* __restrict__ Vt, const int* __restrict__ cnt,
    f16* __restrict__ ctx)
{
  __shared__ f16 Kb[2][32][128];   // K only, 16 KB

  const int bid = blockIdx.x;
  const int xcd = bid & 7, slot = bid >> 3;        // slot 0..63
  const int bh = xcd * 4 + (slot >> 4);            // 0..31
  const int qb = slot & 15;
  const int b  = bh >> 4, h = bh & (NHEADS - 1);
  const int t = threadIdx.x, l = t & 63, w = t >> 6;
  const int r31 = l & 31, hi = l >> 5;
  const int Rm = r31 & 15;
  const int q0 = qb * 128 + w * 32;

  const int c = cnt[b];
  const int NTc = (c + 63) >> 6;

  const f16* Qp = Q + (size_t)bh * SEQ * DK;
  const f16* Kp = K + (size_t)bh * SEQ * DK;
  const f16* Vp = Vt + (size_t)bh * DK * SEQ;

  f16x8 qf[4];
  #pragma unroll
  for (int ds = 0; ds < 4; ++ds)
    qf[ds] = ld_f16x8_g(Qp + (size_t)(q0 + r31) * DK + ds*16 + hi*8);

  // per-lane V row pointers: dt=0 -> d=r31, dt=1 -> d=r31+32; k-offset hi*8
  const f16* vrow[2] = { Vp + (size_t)r31 * SEQ + hi*8,
                         Vp + (size_t)(r31 + 32) * SEQ + hi*8 };

  f32x16 o[2] = {};
  float mrow = -3e38f;
  float lsum = 0.f;

  auto stageK = [&](int buf, int kt) {
    #pragma unroll
    for (int cc = 0; cc < 2; ++cc) {
      int Rbase = w*8 + cc*4;
      int R = Rbase + (l >> 4);
      int u = (l & 15) ^ (R & 15);
      int off32 = (u >> 3) * 32;
      int byteoff = (u & 7) * 16;
      gl_lds16((const char*)Kp + (size_t)(kt + off32 + R) * (DK*2) + byteoff,
               &Kb[buf][Rbase][0]);
    }
  };

  stageK(0, 0);

  for (int it = 0; it < NTc; ++it) {
    __syncthreads();
    if (it + 1 < NTc) stageK((it + 1) & 1, (it + 1) * 64);
    const int kt = it * 64;
    const char* kb = (const char*)&Kb[it & 1][0][0];

    // --- issue V fragment loads early (consumed after softmax; L2 latency hidden)
    f16x8 vfr[2][4];                       // [dt][m]: d = dt*32+r31, k = kt+m*16+hi*8
    #pragma unroll
    for (int dt = 0; dt < 2; ++dt)
      #pragma unroll
      for (int m = 0; m < 4; ++m)
        vfr[dt][m] = ld_f16x8_g(vrow[dt] + kt + m*16);

    // --- bias -> QK C-init
    f32x16 p[2];
    if (kt + 64 <= c) {
      #pragma unroll
      for (int T = 0; T < 2; ++T)
        #pragma unroll
        for (int r = 0; r < 16; ++r) p[T][r] = 0.f;
    } else {
      #pragma unroll
      for (int T = 0; T < 2; ++T)
        #pragma unroll
        for (int r = 0; r < 16; ++r) {
          int k = kt + T*32 + 4*hi + (r & 3) + 8*(r >> 2);
          p[T][r] = (k < c) ? 0.f : MASKVAL;
        }
    }

    __builtin_amdgcn_s_setprio(1);
    #pragma unroll
    for (int T = 0; T < 2; ++T)
      #pragma unroll
      for (int ds = 0; ds < 4; ++ds) {
        int slotc = T*8 + ds*2 + hi;
        f16x8 kf = *(const f16x8*)(kb + r31*256 + ((slotc ^ Rm) << 4));
        p[T] = __builtin_amdgcn_mfma_f32_32x32x16_f16(kf, qf[ds], p[T], 0, 0, 0);
      }
    __builtin_amdgcn_s_setprio(0);

    float mx;
    {
      f32x4 t4;
      #pragma unroll
      for (int r = 0; r < 4; ++r)
        t4[r] = fmaxf(fmaxf(p[0][r], p[0][r+4]), fmaxf(p[0][r+8], p[0][r+12]));
      #pragma unroll
      for (int r = 0; r < 4; ++r)
        t4[r] = fmaxf(t4[r], fmaxf(fmaxf(p[1][r], p[1][r+4]), fmaxf(p[1][r+8], p[1][r+12])));
      mx = fmaxf(fmaxf(t4[0], t4[1]), fmaxf(t4[2], t4[3]));
    }
    mx = fmaxf(mx, __shfl_xor(mx, 32));

    if (!__all(mx <= mrow + 8.f)) {
      float nm = fmaxf(mrow, mx);
      float sc = __builtin_amdgcn_exp2f(mrow - nm);
      mrow = nm;
      lsum *= sc;
      #pragma unroll
      for (int dt = 0; dt < 2; ++dt)
        #pragma unroll
        for (int r = 0; r < 16; ++r) o[dt][r] *= sc;
    }

    f16x2 h2[2][8];
    float s0 = 0.f, s1 = 0.f;
    #pragma unroll
    for (int T = 0; T < 2; ++T)
      #pragma unroll
      for (int rp = 0; rp < 8; ++rp) {
        float e0 = __builtin_amdgcn_exp2f(p[T][2*rp]   - mrow);
        float e1 = __builtin_amdgcn_exp2f(p[T][2*rp+1] - mrow);
        s0 += e0; s1 += e1;
        h2[T][rp] = cvt_pk(e0, e1);
      }
    lsum += s0 + s1;

    __builtin_amdgcn_s_setprio(1);
    #pragma unroll
    for (int T = 0; T < 2; ++T)
      #pragma unroll
      for (int half = 0; half < 2; ++half) {
        union { f16x2 a[4]; f16x8 v8; } pu;
        pu.a[0] = h2[T][half*4+0]; pu.a[1] = h2[T][half*4+1];
        pu.a[2] = h2[T][half*4+2]; pu.a[3] = h2[T][half*4+3];
        int m = T*2 + half;
        #pragma unroll
        for (int dt = 0; dt < 2; ++dt)
          o[dt] = __builtin_amdgcn_mfma_f32_32x32x16_f16(vfr[dt][m], pu.v8, o[dt], 0, 0, 0);
      }
    __builtin_amdgcn_s_setprio(0);
  }

  lsum += __shfl_xor(lsum, 32);
  float inv = 1.f / lsum;
  f16* cp = ctx + (size_t)(b*SEQ + q0 + r31) * DMODEL + h*DK;
  #pragma unroll
  for (int dt = 0; dt < 2; ++dt)
    #pragma unroll
    for (int rq = 0; rq < 4; ++rq) {
      union { f16x2 h2v[2]; f16x4 h4v; } u;
      u.h2v[0] = cvt_pk(o[dt][4*rq+0]*inv, o[dt][4*rq+1]*inv);
      u.h2v[1] = cvt_pk(o[dt][4*rq+2]*inv, o[dt][4*rq+3]*inv);
      *(f16x4*)(cp + dt*32 + 8*rq + 4*hi) = u.h4v;
    }
}

extern "C" void kernel_launch(void* const* d_in, const int* in_sizes, int n_in,
                              void* d_out, int out_size, void* d_ws, size_t ws_size,
                              hipStream_t stream) {
  const float* x    = (const float*)d_in[0];
  const int*   mask = (const int*)d_in[1];
  const float* Wqkv = (const float*)d_in[2];
  const float* bqkv = (const float*)d_in[3];
  const float* Wout = (const float*)d_in[4];
  const float* bout = (const float*)d_in[5];
  float* out = (float*)d_out;

  const size_t SZ_X    = (size_t)MTOT * DMODEL * 2;
  const size_t SZ_WQKV = (size_t)NQKV * DMODEL * 2;
  const size_t SZ_WOUT = (size_t)DMODEL * DMODEL * 2;
  const size_t SZ_QKV  = (size_t)BATCH * NHEADS * SEQ * DK * 2;
  const size_t SZ_INV  = (size_t)MTOT * 4;    // inv: 4096 ints
  const size_t SZ_CNT  = 256;
  const size_t NEED = SZ_X + SZ_WQKV + SZ_WOUT + 3*SZ_QKV + SZ_X + SZ_INV + SZ_CNT;
  if (ws_size < NEED) return;

  char* p = (char*)d_ws;
  f16* xh    = (f16*)p; p += SZ_X;
  f16* Wqkvt = (f16*)p; p += SZ_WQKV;
  f16* Woutt = (f16*)p; p += SZ_WOUT;
  f16* Qh    = (f16*)p; p += SZ_QKV;
  f16* Kh    = (f16*)p; p += SZ_QKV;
  f16* Vth   = (f16*)p; p += SZ_QKV;
  f16* ctx   = (f16*)p; p += SZ_X;
  int* inv   = (int*)p; p += SZ_INV;
  int* cnt   = (int*)p; p += SZ_CNT;

  k_prep<<<4096 + 3072 + 1024 + BATCH, 256, 0, stream>>>(
      x, xh, Wqkv, Wqkvt, Wout, Woutt, mask, inv, cnt);

  k_gemm_qkv2<<<512 + 1024, 256, 0, stream>>>(
      xh, Wqkvt, bqkv, inv, cnt, Qh, Kh, Vth, DMODEL);

  k_attn13<<<32 * 16, 256, 0, stream>>>(Qh, Kh, Vth, cnt, ctx);

  k_gemm_out<<<dim3(DMODEL/128, MTOT/64), 256, 0, stream>>>(
      ctx, Woutt, bout, out, DMODEL, DMODEL);
}

// Round 23
// 96.648 us; speedup vs baseline: 1.0648x; 1.0648x over previous
//
#include <hip/hip_runtime.h>

typedef _Float16 f16;
typedef _Float16 f16x2 __attribute__((ext_vector_type(2)));
typedef _Float16 f16x4 __attribute__((ext_vector_type(4)));
typedef _Float16 f16x8 __attribute__((ext_vector_type(8)));
typedef float    f32x4 __attribute__((ext_vector_type(4)));
typedef float    f32x16 __attribute__((ext_vector_type(16)));
typedef int      i32x4 __attribute__((ext_vector_type(4)));

#define NHEADS 16
#define DK 64
#define BATCH 2
#define SEQ 2048
#define DMODEL 1024
#define MTOT (BATCH*SEQ)          // 4096
#define NQKV (3*DMODEL)           // 3072
#define NBH  (BATCH*NHEADS)       // 32
#define LOG2E 1.44269504f
#define QSCALE (0.125f * LOG2E)   // fold 1/sqrt(dk) and log2(e) into Q
#define MASKVAL (-10000.0f * LOG2E)

__device__ inline f16x8 ld_f16x8_g(const f16* p) {
  return __builtin_bit_cast(f16x8, *reinterpret_cast<const i32x4*>(p));
}

__device__ inline f16x2 cvt_pk(float a, float b) {
  return __builtin_bit_cast(f16x2, __builtin_amdgcn_cvt_pkrtz(a, b));
}

__device__ inline void gl_lds16(const void* g, void* l) {
  __builtin_amdgcn_global_load_lds(
      (const __attribute__((address_space(1))) unsigned int*)g,
      (__attribute__((address_space(3))) unsigned int*)l, 16, 0, 0);
}

// sigma: swap bits 2,3 (involution) -- the V^T column permutation for 32x32 PV
__device__ inline int sigma_k(int s) {
  return (s & ~12) | ((s & 4) << 1) | ((s & 8) >> 1);
}

// ---------------- fused preprocessing: cvt + 2 tcvts + mask scan -----------------
__device__ inline void tcvt_tile(float (*tile)[33], const float* __restrict__ in,
                                 f16* __restrict__ out, int K, int N, int k0, int n0) {
  const int t = threadIdx.x, j = t & 7, ty = t >> 3;   // j: 4-col group, ty: row 0..31
  float4 v = *reinterpret_cast<const float4*>(in + (size_t)(k0 + ty) * N + n0 + j*4);
  tile[ty][j*4+0] = v.x; tile[ty][j*4+1] = v.y;
  tile[ty][j*4+2] = v.z; tile[ty][j*4+3] = v.w;
  __syncthreads();
  union { f16x2 h2[2]; f16x4 h4; } u;
  u.h2[0] = cvt_pk(tile[j*4+0][ty], tile[j*4+1][ty]);
  u.h2[1] = cvt_pk(tile[j*4+2][ty], tile[j*4+3][ty]);
  *(f16x4*)(out + (size_t)(n0 + ty) * K + k0 + j*4) = u.h4;
}

__global__ __launch_bounds__(256) void k_prep(
    const float* __restrict__ x, f16* __restrict__ xh,
    const float* __restrict__ Wqkv, f16* __restrict__ Wqkvt,
    const float* __restrict__ Wout, f16* __restrict__ Woutt,
    const int* __restrict__ mask, int* __restrict__ inv, int* __restrict__ cnt)
{
  __shared__ float tile[32][33];
  __shared__ int part[256];
  const int bid = blockIdx.x;
  const int t = threadIdx.x;
  if (bid < 4096) {
    int i = (bid * 256 + t) * 4;
    float4 v = *reinterpret_cast<const float4*>(x + i);
    f16x4 o = { (f16)v.x, (f16)v.y, (f16)v.z, (f16)v.w };
    *reinterpret_cast<f16x4*>(xh + i) = o;
  } else if (bid < 4096 + 3072) {
    int tl = bid - 4096;                       // 96 n-tiles x 32 k-tiles
    tcvt_tile(tile, Wqkv, Wqkvt, DMODEL, NQKV, (tl / 96) * 32, (tl % 96) * 32);
  } else if (bid < 8192) {
    int tl = bid - 4096 - 3072;                // 32 x 32
    tcvt_tile(tile, Wout, Woutt, DMODEL, DMODEL, (tl / 32) * 32, (tl % 32) * 32);
  } else {
    // deterministic per-batch scan
    const int b = bid - 8192;
    const int* mp = mask + b * SEQ;
    int* iv = inv + b * SEQ;
    const int base = t * 8;
    int m[8]; int s = 0;
    #pragma unroll
    for (int i = 0; i < 8; ++i) { m[i] = mp[base + i]; s += (m[i] != 0); }
    part[t] = s;
    __syncthreads();
    for (int d = 1; d < 256; d <<= 1) {
      int v = (t >= d) ? part[t - d] : 0;
      __syncthreads();
      part[t] += v;
      __syncthreads();
    }
    int pos = (t == 0) ? 0 : part[t - 1];
    #pragma unroll
    for (int i = 0; i < 8; ++i) {
      if (m[i] != 0) { iv[pos] = base + i; ++pos; }
    }
    if (t == 255) cnt[b] = part[255];
  }
}

// ---------------- merged QKV GEMM, DOUBLE-BUFFERED 64x128 tile -------------------
__global__ __launch_bounds__(256, 2) void k_gemm_qkv2(
    const f16* __restrict__ A, const f16* __restrict__ Bt,
    const float* __restrict__ bias, const int* __restrict__ inv,
    const int* __restrict__ cnt,
    f16* __restrict__ qo, f16* __restrict__ ko, f16* __restrict__ vto, int K)
{
  __shared__ f16 As[2][64][64];    // 16 KB
  __shared__ f16 Bs[2][128][64];   // 32 KB
  const int bid = blockIdx.x;
  const bool isQ = bid < 512;

  const int t = threadIdx.x;
  const int l = t & 63, w = t >> 6;
  const int lc = l & 15, g = l >> 4;
  const int srow = l >> 3;
  const int ssl  = ((l & 7) ^ srow) * 16;
  const int swz  = (lc & 7) << 4;

  int m0, n0, b = 0, c = 0;
  const f16* Btp;
  const float* biasp;
  size_t aoff[2];
  if (isQ) {
    n0 = (bid & 7) * 128;  m0 = (bid >> 3) * 64;
    Btp = Bt;  biasp = bias;
    #pragma unroll
    for (int it = 0; it < 2; ++it)
      aoff[it] = (size_t)(m0 + it*32 + w*8 + srow) * K;
  } else {
    const int idx = bid - 512;
    n0 = (idx & 15) * 128;  m0 = (idx >> 4) * 64;
    b = m0 >> 11;
    const int sl0 = m0 & (SEQ - 1);
    c = cnt[b];
    if (sl0 >= ((c + 63) & ~63)) return;    // block-uniform early exit
    Btp = Bt + (size_t)DMODEL * DMODEL;     // K/V weight rows
    biasp = bias + DMODEL;
    #pragma unroll
    for (int it = 0; it < 2; ++it) {
      int slot = sl0 + it*32 + w*8 + srow;
      int sidx = (slot < c) ? slot : (c > 0 ? c - 1 : 0);
      aoff[it] = (size_t)(b * SEQ + (inv[b * SEQ + sidx] & (SEQ - 1))) * K;
    }
  }

  auto stage = [&](int buf, int kt) {
    #pragma unroll
    for (int it = 0; it < 2; ++it)
      gl_lds16((const char*)(A + aoff[it] + kt) + ssl, &As[buf][it*32 + w*8][0]);
    #pragma unroll
    for (int it = 0; it < 4; ++it) {
      int row = it*32 + w*8 + srow;
      gl_lds16((const char*)(Btp + (size_t)(n0 + row) * K + kt) + ssl,
               &Bs[buf][it*32 + w*8][0]);
    }
  };

  f32x4 acc[4][2] = {};
  const int NTk = K >> 6;
  stage(0, 0);

  for (int ti = 0; ti < NTk; ++ti) {
    __syncthreads();                          // stage(ti) complete
    if (ti + 1 < NTk) stage((ti + 1) & 1, (ti + 1) * 64);
    const char* abase = (const char*)&As[ti & 1][0][0];
    const char* bbase = (const char*)&Bs[ti & 1][0][0];
    #pragma unroll
    for (int ks = 0; ks < 64; ks += 32) {
      f16x8 af[4], bf[2];
      #pragma unroll
      for (int i = 0; i < 4; ++i)
        af[i] = *(const f16x8*)(abase + (i*16 + lc)*128 + ((ks*2 + g*16) ^ swz));
      #pragma unroll
      for (int j = 0; j < 2; ++j)
        bf[j] = *(const f16x8*)(bbase + (w*32 + j*16 + lc)*128 + ((ks*2 + g*16) ^ swz));
      #pragma unroll
      for (int i = 0; i < 4; ++i)
        #pragma unroll
        for (int j = 0; j < 2; ++j)
          acc[i][j] = __builtin_amdgcn_mfma_f32_16x16x32_f16(af[i], bf[j], acc[i][j], 0, 0, 0);
    }
  }

  if (isQ) {
    #pragma unroll
    for (int i = 0; i < 4; ++i) {
      const int row0 = m0 + i*16 + g*4;
      const int qb = row0 >> 11, s0 = row0 & (SEQ - 1);
      #pragma unroll
      for (int j = 0; j < 2; ++j) {
        int col = n0 + w*32 + j*16 + lc;      // [0,1024)
        float bv = biasp[col];
        int h = col >> 6, d = col & 63;
        size_t bh = (size_t)(qb * NHEADS + h);
        #pragma unroll
        for (int r = 0; r < 4; ++r)
          qo[(bh * SEQ + s0 + r) * DK + d] = (f16)((acc[i][j][r] + bv) * QSCALE);
      }
    }
  } else {
    const int sl0 = m0 & (SEQ - 1);
    #pragma unroll
    for (int i = 0; i < 4; ++i) {
      const int slot0 = sl0 + i*16 + g*4;     // 4-aligned; sigma(slot0)+r contiguous
      #pragma unroll
      for (int j = 0; j < 2; ++j) {
        int colkv = n0 + w*32 + j*16 + lc;    // [0,2048)
        float bv = biasp[colkv];
        int kv = colkv >> 10;                 // block-uniform
        int h = (colkv >> 6) & 15, d = colkv & 63;
        size_t bh = (size_t)(b * NHEADS + h);
        if (kv == 0) {
          #pragma unroll
          for (int r = 0; r < 4; ++r)
            ko[(bh * SEQ + slot0 + r) * DK + d] = (f16)(acc[i][j][r] + bv);
        } else {
          union { f16x2 h2[2]; f16x4 h4; } u;
          u.h2[0] = cvt_pk(acc[i][j][0] + bv, acc[i][j][1] + bv);
          u.h2[1] = cvt_pk(acc[i][j][2] + bv, acc[i][j][3] + bv);
          *(f16x4*)(vto + (bh * DK + d) * SEQ + sigma_k(slot0)) = u.h4;
        }
      }
    }
  }
}

// ---------------- out-proj GEMM, DOUBLE-BUFFERED 64x128 tile ---------------------
__global__ __launch_bounds__(256, 2) void k_gemm_out(
    const f16* __restrict__ A, const f16* __restrict__ Bt,
    const float* __restrict__ bias, float* __restrict__ outf, int N, int K)
{
  __shared__ f16 As[2][64][64];    // 16 KB
  __shared__ f16 Bs[2][128][64];   // 32 KB
  const int m0 = blockIdx.y * 64, n0 = blockIdx.x * 128;
  const int t = threadIdx.x;
  const int l = t & 63, w = t >> 6;
  const int lc = l & 15, g = l >> 4;
  const int srow = l >> 3;
  const int ssl  = ((l & 7) ^ srow) * 16;
  const int swz  = (lc & 7) << 4;

  auto stage = [&](int buf, int kt) {
    #pragma unroll
    for (int it = 0; it < 2; ++it) {
      int row = it*32 + w*8 + srow;
      gl_lds16((const char*)(A + (size_t)(m0 + row) * K + kt) + ssl,
               &As[buf][it*32 + w*8][0]);
    }
    #pragma unroll
    for (int it = 0; it < 4; ++it) {
      int row = it*32 + w*8 + srow;
      gl_lds16((const char*)(Bt + (size_t)(n0 + row) * K + kt) + ssl,
               &Bs[buf][it*32 + w*8][0]);
    }
  };

  f32x4 acc[4][2] = {};
  const int NTk = K >> 6;
  stage(0, 0);

  for (int ti = 0; ti < NTk; ++ti) {
    __syncthreads();
    if (ti + 1 < NTk) stage((ti + 1) & 1, (ti + 1) * 64);
    const char* abase = (const char*)&As[ti & 1][0][0];
    const char* bbase = (const char*)&Bs[ti & 1][0][0];
    #pragma unroll
    for (int ks = 0; ks < 64; ks += 32) {
      f16x8 af[4], bf[2];
      #pragma unroll
      for (int i = 0; i < 4; ++i)
        af[i] = *(const f16x8*)(abase + (i*16 + lc)*128 + ((ks*2 + g*16) ^ swz));
      #pragma unroll
      for (int j = 0; j < 2; ++j)
        bf[j] = *(const f16x8*)(bbase + (w*32 + j*16 + lc)*128 + ((ks*2 + g*16) ^ swz));
      #pragma unroll
      for (int i = 0; i < 4; ++i)
        #pragma unroll
        for (int j = 0; j < 2; ++j)
          acc[i][j] = __builtin_amdgcn_mfma_f32_16x16x32_f16(af[i], bf[j], acc[i][j], 0, 0, 0);
    }
  }

  #pragma unroll
  for (int i = 0; i < 4; ++i) {
    #pragma unroll
    for (int j = 0; j < 2; ++j) {
      int col = n0 + w*32 + j*16 + lc;
      float bv = bias[col];
      #pragma unroll
      for (int r = 0; r < 4; ++r) {
        int row = m0 + i*16 + g*4 + r;
        outf[(size_t)row * N + col] = acc[i][j][r] + bv;
      }
    }
  }
}

// ---------------- flash attention v10 (best: ~34 us): compacted keys -------------
__global__ __launch_bounds__(256, 2) void k_attn10(
    const f16* __restrict__ Q, const f16* __restrict__ K,
    const f16* __restrict__ Vt, const int* __restrict__ cnt,
    f16* __restrict__ ctx)
{
  __shared__ f16 Kb[2][32][128];
  __shared__ f16 Vb[2][32][128];

  const int bid = blockIdx.x;
  const int xcd = bid & 7, slot = bid >> 3;        // slot 0..63
  const int bh = xcd * 4 + (slot >> 4);            // 0..31
  const int qb = slot & 15;
  const int b  = bh >> 4, h = bh & (NHEADS - 1);
  const int t = threadIdx.x, l = t & 63, w = t >> 6;
  const int r31 = l & 31, hi = l >> 5;
  const int Rm = r31 & 15;
  const int q0 = qb * 128 + w * 32;

  const int c = cnt[b];
  const int NTc = (c + 63) >> 6;

  const f16* Qp = Q + (size_t)bh * SEQ * DK;
  const f16* Kp = K + (size_t)bh * SEQ * DK;
  const f16* Vp = Vt + (size_t)bh * DK * SEQ;

  f16x8 qf[4];
  #pragma unroll
  for (int ds = 0; ds < 4; ++ds)
    qf[ds] = ld_f16x8_g(Qp + (size_t)(q0 + r31) * DK + ds*16 + hi*8);

  f32x16 o[2] = {};
  float mrow = -3e38f;
  float lsum = 0.f;

  auto stage = [&](int buf, int kt) {
    #pragma unroll
    for (int cc = 0; cc < 2; ++cc) {
      int Rbase = w*8 + cc*4;
      int R = Rbase + (l >> 4);
      int u = (l & 15) ^ (R & 15);
      int off32 = (u >> 3) * 32;
      int byteoff = (u & 7) * 16;
      gl_lds16((const char*)Kp + (size_t)(kt + off32 + R) * (DK*2) + byteoff,
               &Kb[buf][Rbase][0]);
      gl_lds16((const char*)Vp + (size_t)(off32 + R) * (SEQ*2) + (size_t)kt*2 + byteoff,
               &Vb[buf][Rbase][0]);
    }
  };

  stage(0, 0);

  for (int it = 0; it < NTc; ++it) {
    __syncthreads();
    if (it + 1 < NTc) stage((it + 1) & 1, (it + 1) * 64);
    const int kt = it * 64;
    const char* kb = (const char*)&Kb[it & 1][0][0];
    const char* vb = (const char*)&Vb[it & 1][0][0];

    f32x16 p[2];
    if (kt + 64 <= c) {
      #pragma unroll
      for (int T = 0; T < 2; ++T)
        #pragma unroll
        for (int r = 0; r < 16; ++r) p[T][r] = 0.f;
    } else {
      #pragma unroll
      for (int T = 0; T < 2; ++T)
        #pragma unroll
        for (int r = 0; r < 16; ++r) {
          int k = kt + T*32 + 4*hi + (r & 3) + 8*(r >> 2);
          p[T][r] = (k < c) ? 0.f : MASKVAL;
        }
    }

    __builtin_amdgcn_s_setprio(1);
    #pragma unroll
    for (int T = 0; T < 2; ++T)
      #pragma unroll
      for (int ds = 0; ds < 4; ++ds) {
        int slotc = T*8 + ds*2 + hi;
        f16x8 kf = *(const f16x8*)(kb + r31*256 + ((slotc ^ Rm) << 4));
        p[T] = __builtin_amdgcn_mfma_f32_32x32x16_f16(kf, qf[ds], p[T], 0, 0, 0);
      }
    __builtin_amdgcn_s_setprio(0);

    float mx;
    {
      f32x4 t4;
      #pragma unroll
      for (int r = 0; r < 4; ++r)
        t4[r] = fmaxf(fmaxf(p[0][r], p[0][r+4]), fmaxf(p[0][r+8], p[0][r+12]));
      #pragma unroll
      for (int r = 0; r < 4; ++r)
        t4[r] = fmaxf(t4[r], fmaxf(fmaxf(p[1][r], p[1][r+4]), fmaxf(p[1][r+8], p[1][r+12])));
      mx = fmaxf(fmaxf(t4[0], t4[1]), fmaxf(t4[2], t4[3]));
    }
    mx = fmaxf(mx, __shfl_xor(mx, 32));

    if (!__all(mx <= mrow + 8.f)) {
      float nm = fmaxf(mrow, mx);
      float sc = __builtin_amdgcn_exp2f(mrow - nm);
      mrow = nm;
      lsum *= sc;
      #pragma unroll
      for (int dt = 0; dt < 2; ++dt)
        #pragma unroll
        for (int r = 0; r < 16; ++r) o[dt][r] *= sc;
    }

    f16x2 h2[2][8];
    float s0 = 0.f, s1 = 0.f;
    #pragma unroll
    for (int T = 0; T < 2; ++T)
      #pragma unroll
      for (int rp = 0; rp < 8; ++rp) {
        float e0 = __builtin_amdgcn_exp2f(p[T][2*rp]   - mrow);
        float e1 = __builtin_amdgcn_exp2f(p[T][2*rp+1] - mrow);
        s0 += e0; s1 += e1;
        h2[T][rp] = cvt_pk(e0, e1);
      }
    lsum += s0 + s1;

    __builtin_amdgcn_s_setprio(1);
    #pragma unroll
    for (int T = 0; T < 2; ++T)
      #pragma unroll
      for (int half = 0; half < 2; ++half) {
        union { f16x2 a[4]; f16x8 v8; } pu;
        pu.a[0] = h2[T][half*4+0]; pu.a[1] = h2[T][half*4+1];
        pu.a[2] = h2[T][half*4+2]; pu.a[3] = h2[T][half*4+3];
        int m = T*2 + half;
        #pragma unroll
        for (int dt = 0; dt < 2; ++dt) {
          int slotc = dt*8 + m*2 + hi;
          f16x8 vf = *(const f16x8*)(vb + r31*256 + ((slotc ^ Rm) << 4));
          o[dt] = __builtin_amdgcn_mfma_f32_32x32x16_f16(vf, pu.v8, o[dt], 0, 0, 0);
        }
      }
    __builtin_amdgcn_s_setprio(0);
  }

  lsum += __shfl_xor(lsum, 32);
  float inv = 1.f / lsum;
  f16* cp = ctx + (size_t)(b*SEQ + q0 + r31) * DMODEL + h*DK;
  #pragma unroll
  for (int dt = 0; dt < 2; ++dt)
    #pragma unroll
    for (int rq = 0; rq < 4; ++rq) {
      union { f16x2 h2v[2]; f16x4 h4v; } u;
      u.h2v[0] = cvt_pk(o[dt][4*rq+0]*inv, o[dt][4*rq+1]*inv);
      u.h2v[1] = cvt_pk(o[dt][4*rq+2]*inv, o[dt][4*rq+3]*inv);
      *(f16x4*)(cp + dt*32 + 8*rq + 4*hi) = u.h4v;
    }
}

extern "C" void kernel_launch(void* const* d_in, const int* in_sizes, int n_in,
                              void* d_out, int out_size, void* d_ws, size_t ws_size,
                              hipStream_t stream) {
  const float* x    = (const float*)d_in[0];
  const int*   mask = (const int*)d_in[1];
  const float* Wqkv = (const float*)d_in[2];
  const float* bqkv = (const float*)d_in[3];
  const float* Wout = (const float*)d_in[4];
  const float* bout = (const float*)d_in[5];
  float* out = (float*)d_out;

  const size_t SZ_X    = (size_t)MTOT * DMODEL * 2;
  const size_t SZ_WQKV = (size_t)NQKV * DMODEL * 2;
  const size_t SZ_WOUT = (size_t)DMODEL * DMODEL * 2;
  const size_t SZ_QKV  = (size_t)BATCH * NHEADS * SEQ * DK * 2;
  const size_t SZ_INV  = (size_t)MTOT * 4;    // inv: 4096 ints
  const size_t SZ_CNT  = 256;
  const size_t NEED = SZ_X + SZ_WQKV + SZ_WOUT + 3*SZ_QKV + SZ_X + SZ_INV + SZ_CNT;
  if (ws_size < NEED) return;

  char* p = (char*)d_ws;
  f16* xh    = (f16*)p; p += SZ_X;
  f16* Wqkvt = (f16*)p; p += SZ_WQKV;
  f16* Woutt = (f16*)p; p += SZ_WOUT;
  f16* Qh    = (f16*)p; p += SZ_QKV;
  f16* Kh    = (f16*)p; p += SZ_QKV;
  f16* Vth   = (f16*)p; p += SZ_QKV;
  f16* ctx   = (f16*)p; p += SZ_X;
  int* inv   = (int*)p; p += SZ_INV;
  int* cnt   = (int*)p; p += SZ_CNT;

  k_prep<<<4096 + 3072 + 1024 + BATCH, 256, 0, stream>>>(
      x, xh, Wqkv, Wqkvt, Wout, Woutt, mask, inv, cnt);

  k_gemm_qkv2<<<512 + 1024, 256, 0, stream>>>(
      xh, Wqkvt, bqkv, inv, cnt, Qh, Kh, Vth, DMODEL);

  k_attn10<<<32 * 16, 256, 0, stream>>>(Qh, Kh, Vth, cnt, ctx);

  k_gemm_out<<<dim3(DMODEL/128, MTOT/64), 256, 0, stream>>>(
      ctx, Woutt, bout, out, DMODEL, DMODEL);
}